// Round 7
// baseline (23852.068 us; speedup 1.0000x reference)
//
#include <hip/hip_runtime.h>

#define R7_K 4096
#define R7_N 11008
#define R7_NZ8 (R7_N / 8)   // 1376

// ROUND 7: scalar reference probe with scales read as F32 (r6 telemetry:
// u16[0] of d_in[3] = 0x8000 = low-mantissa half of an fp16-origin f32;
// -0.0 under any 2-byte decode => scales are f32-stored).
// Exact transcription of the reference formula, fp32 math throughout.
// absmax fingerprint: <=29 PASS (f32 confirmed); ~1464 => fp16-stored;
// ~2000-4000 => bf16-stored.
__global__ __launch_bounds__(256)
void r7_gptq_scalar_f32scales(const float* __restrict__ xin,
                              const int*   __restrict__ qw,
                              const int*   __restrict__ qz,
                              const float* __restrict__ scl,
                              const float* __restrict__ bvec,
                              float* __restrict__ outp)
{
    const int t    = threadIdx.x;
    const int ncol = blockIdx.x * 64 + (t & 63);       // global output column
    const int row0 = blockIdx.y * 16 + (t >> 6) * 4;   // first of 4 owned rows

    float a0 = 0.f, a1 = 0.f, a2 = 0.f, a3 = 0.f;

    for (int g = 0; g < 32; ++g) {
        const float s  = scl[(size_t)g * R7_N + ncol];         // f32 scales
        const unsigned zw = (unsigned)qz[(size_t)g * R7_NZ8 + (ncol >> 3)];
        const float z  = (float)((zw >> ((ncol & 7) * 4)) & 15u);
        const float mz = -s * z;

        for (int kk = 0; kk < 128; ++kk) {
            const int k = g * 128 + kk;
            const unsigned qv = (unsigned)qw[(size_t)(k >> 3) * R7_N + ncol];
            const float wq = (float)((qv >> ((k & 7) * 4)) & 15u);
            const float wd = __builtin_fmaf(s, wq, mz);        // s*(w-z)
            a0 = __builtin_fmaf(xin[(size_t)(row0 + 0) * R7_K + k], wd, a0);
            a1 = __builtin_fmaf(xin[(size_t)(row0 + 1) * R7_K + k], wd, a1);
            a2 = __builtin_fmaf(xin[(size_t)(row0 + 2) * R7_K + k], wd, a2);
            a3 = __builtin_fmaf(xin[(size_t)(row0 + 3) * R7_K + k], wd, a3);
        }
    }

    const float bb = bvec[ncol];
    outp[(size_t)(row0 + 0) * R7_N + ncol] = a0 + bb;
    outp[(size_t)(row0 + 1) * R7_N + ncol] = a1 + bb;
    outp[(size_t)(row0 + 2) * R7_N + ncol] = a2 + bb;
    outp[(size_t)(row0 + 3) * R7_N + ncol] = a3 + bb;
}

extern "C" void kernel_launch(void* const* d_in, const int* in_sizes, int n_in,
                              void* d_out, int out_size, void* d_ws, size_t ws_size,
                              hipStream_t stream)
{
    const float* xin = (const float*)d_in[0];
    const int*   qw  = (const int*)d_in[1];
    const int*   qz  = (const int*)d_in[2];
    const float* scl = (const float*)d_in[3];
    const float* bvec = (const float*)d_in[4];
    float* outp = (float*)d_out;

    dim3 grid(R7_N / 64, 4096 / 16);   // (172, 256)
    hipLaunchKernelGGL(r7_gptq_scalar_f32scales, grid, dim3(256), 0, stream,
                       xin, qw, qz, scl, bvec, outp);
}

// Round 8
// 492.386 us; speedup vs baseline: 48.4418x; 48.4418x over previous
//
#include <hip/hip_runtime.h>
#include <hip/hip_bf16.h>

#define K_DIM 4096
#define N_DIM 11008
#define NT_N  86            // N_DIM / 128
#define NZ8   (N_DIM / 8)   // 1376

typedef __bf16 bf16x8 __attribute__((ext_vector_type(8)));
typedef float  f32x4  __attribute__((ext_vector_type(4)));

// Fused GPTQ dequant + GEMM. r8 = r1 machinery + f32 scales (r7-validated).
// Tile: BM=128, BN=128, BK=64. 256 threads = 4 waves (2x2), wave = 64x64 out.
// MFMA 16x16x32 bf16, acc 4x4 fragments per wave.
// LDS: A [row 128][k 64] bf16, B [n 128][k 64] bf16 (k-contig per n).
// Both XOR-swizzled: physical_byte = row*128 + (logical_off ^ ((row&7)<<4)).
__global__ __launch_bounds__(256, 2)
void r8_gptq_mfma(const float* __restrict__ x,
                  const int*   __restrict__ qweight,
                  const int*   __restrict__ qzeros,
                  const float* __restrict__ scales,
                  const float* __restrict__ bias,
                  float* __restrict__ out)
{
    __shared__ __align__(16) unsigned char Asm[128 * 64 * 2];
    __shared__ __align__(16) unsigned char Bsm[128 * 64 * 2];

    const int tid  = threadIdx.x;
    const int lane = tid & 63;
    const int wv   = tid >> 6;
    const int wr   = (wv >> 1) * 64;   // wave row offset in tile
    const int wc   = (wv & 1) * 64;    // wave col offset in tile

    // XCD-aware bijective swizzle (gridDim.x = 2752, divisible by 8)
    int bid = blockIdx.x;
    const int cpx = gridDim.x >> 3;
    bid = (bid & 7) * cpx + (bid >> 3);
    const int bm0 = (bid / NT_N) * 128;
    const int bn0 = (bid % NT_N) * 128;

    // ---- A staging: 128x64 fp32->bf16. 16 threads/row-base, 8 row-passes.
    const int ar  = tid >> 4;          // 0..15
    const int ac4 = tid & 15;          // float4 column (k = ac4*4)
    const float* xp = x + (size_t)(bm0 + ar) * K_DIM + ac4 * 4;
    unsigned char* aw = Asm + ar * 128 + ((ac4 * 8) ^ ((ar & 7) << 4));

    // ---- B staging: each thread owns column n = tid&127, row-parity tid>>7.
    const int bnn  = tid & 127;
    const int bk8q = tid >> 7;         // 0..1
    const int ngl  = bn0 + bnn;
    const int* qwp = qweight + (size_t)bk8q * N_DIM + ngl;
    unsigned char* bw = Bsm + bnn * 128;
    const int bsw = bnn & 7;

    // ---- fragment constants
    const int frow = lane & 15;
    const int kb8  = lane >> 4;        // k-chunk: k = chunk*8 + e
    const int fsw  = frow & 7;

    f32x4 acc[4][4];
#pragma unroll
    for (int m = 0; m < 4; ++m)
#pragma unroll
        for (int n = 0; n < 4; ++n)
            acc[m][n] = (f32x4){0.f, 0.f, 0.f, 0.f};

    float sc = 0.f, nsz = 0.f;

    for (int kt = 0; kt < K_DIM / 64; ++kt) {
        const int k0 = kt * 64;

        // group-constant dequant params (group = 128 k = 2 k-steps)
        if ((k0 & 127) == 0) {
            const int g = k0 >> 7;
            sc = scales[(size_t)g * N_DIM + ngl];            // f32 (r7-validated)
            const unsigned zq = (unsigned)qzeros[(size_t)g * NZ8 + (ngl >> 3)];
            const float zf = (float)((zq >> ((ngl & 7) * 4)) & 15u);
            nsz = -sc * zf;
        }

        // ---- stage A: fp32 -> bf16
#pragma unroll
        for (int i = 0; i < 8; ++i) {
            const float4 v = *(const float4*)(xp + (size_t)i * 16 * K_DIM + k0);
            union { __bf16 h[4]; unsigned long long u; } p;
            p.h[0] = (__bf16)v.x; p.h[1] = (__bf16)v.y;
            p.h[2] = (__bf16)v.z; p.h[3] = (__bf16)v.w;
            *(unsigned long long*)(aw + i * 16 * 128) = p.u;
        }

        // ---- stage B: unpack int4 -> dequant bf16, one b128 write per int32
#pragma unroll
        for (int i = 0; i < 4; ++i) {
            const int k8 = 2 * i + bk8q;               // local qweight row 0..7
            const unsigned q = (unsigned)qwp[(size_t)(kt * 8 + 2 * i) * N_DIM];
            union { __bf16 h[8]; bf16x8 v8; } p;
#pragma unroll
            for (int j = 0; j < 8; ++j) {
                const float w = (float)((q >> (4 * j)) & 15u);
                p.h[j] = (__bf16)__builtin_fmaf(sc, w, nsz);  // sc*(w-z)
            }
            *(bf16x8*)(bw + ((k8 ^ bsw) << 4)) = p.v8;
        }

        __syncthreads();

        // ---- compute: 2 k-halves x 4x4 MFMA
#pragma unroll
        for (int kh = 0; kh < 2; ++kh) {
            const int ksl = (kh << 2) + kb8;           // 16B slot 0..7
            bf16x8 af[4], bfr[4];
#pragma unroll
            for (int m = 0; m < 4; ++m) {
                const int row = wr + m * 16 + frow;
                af[m] = *(const bf16x8*)(Asm + row * 128 + ((ksl ^ fsw) << 4));
            }
#pragma unroll
            for (int n = 0; n < 4; ++n) {
                const int nn = wc + n * 16 + frow;
                bfr[n] = *(const bf16x8*)(Bsm + nn * 128 + ((ksl ^ fsw) << 4));
            }
#pragma unroll
            for (int m = 0; m < 4; ++m)
#pragma unroll
                for (int n = 0; n < 4; ++n)
                    acc[m][n] = __builtin_amdgcn_mfma_f32_16x16x32_bf16(
                        af[m], bfr[n], acc[m][n], 0, 0, 0);
        }

        __syncthreads();
    }

    // ---- epilogue: C row=(lane>>4)*4+j, col=lane&15 (m89 layout)
    const int crow0 = (lane >> 4) << 2;
    const int ccol  = lane & 15;
#pragma unroll
    for (int n = 0; n < 4; ++n) {
        const int col = bn0 + wc + n * 16 + ccol;
        const float bv = bias[col];
#pragma unroll
        for (int m = 0; m < 4; ++m) {
            const int row = bm0 + wr + m * 16 + crow0;
#pragma unroll
            for (int j = 0; j < 4; ++j)
                out[(size_t)(row + j) * N_DIM + col] = acc[m][n][j] + bv;
        }
    }
}

extern "C" void kernel_launch(void* const* d_in, const int* in_sizes, int n_in,
                              void* d_out, int out_size, void* d_ws, size_t ws_size,
                              hipStream_t stream)
{
    const float* x   = (const float*)d_in[0];
    const int*   qw  = (const int*)d_in[1];
    const int*   qz  = (const int*)d_in[2];
    const float* scl = (const float*)d_in[3];
    const float* bs  = (const float*)d_in[4];
    float* out = (float*)d_out;

    const int M = in_sizes[0] / K_DIM;            // 4096
    dim3 grid((M / 128) * NT_N);                  // 32 * 86 = 2752
    hipLaunchKernelGGL(r8_gptq_mfma, grid, dim3(256), 0, stream,
                       x, qw, qz, scl, bs, out);
}

// Round 10
// 414.171 us; speedup vs baseline: 57.5899x; 1.1888x over previous
//
#include <hip/hip_runtime.h>
#include <hip/hip_fp16.h>

#define K_DIM 4096
#define N_DIM 11008
#define NZ8   1376          // N_DIM/8
#define BM    256
#define BN    128
#define NT_N  86            // N_DIM/BN

typedef _Float16 f16x8 __attribute__((ext_vector_type(8)));
typedef float    f32x4 __attribute__((ext_vector_type(4)));

// ---------------- pre-pass: x f32 -> fp16 into ws, k-interleaved ------------
// Within each aligned 8-k chunk, store order (k0,k4,k1,k5,k2,k6,k3,k7) so the
// GEMM's A copy matches the magic-dequant B layout (pairs (k,k+4) per dword).
__global__ __launch_bounds__(256)
void r10_xcvt(const float* __restrict__ x, __half* __restrict__ xh, int nchunks)
{
    int c = blockIdx.x * 256 + threadIdx.x;
    const int stride = gridDim.x * 256;
    for (; c < nchunks; c += stride) {
        const float4 f0 = ((const float4*)x)[2 * c];
        const float4 f1 = ((const float4*)x)[2 * c + 1];
        union { __half2 h2[4]; int4 v; } p;
        p.h2[0] = __floats2half2_rn(f0.x, f1.x);
        p.h2[1] = __floats2half2_rn(f0.y, f1.y);
        p.h2[2] = __floats2half2_rn(f0.z, f1.z);
        p.h2[3] = __floats2half2_rn(f0.w, f1.w);
        ((int4*)xh)[c] = p.v;
    }
}

// ---------------- fused GEMM: tile 256x128, BK=64, 8 waves ------------------
// LDS row = 128B (64 fp16), XOR-swizzled: byte = row*128 + (off ^ ((row&7)<<4)).
// APATH 0: A copied from pre-converted ws (fp16). APATH 1: A from f32 x.
template<int APATH>
__global__ __launch_bounds__(512, 4)
void r10_gptq_mfma(const float* __restrict__ x,
                   const __half* __restrict__ xh,
                   const int*   __restrict__ qweight,
                   const int*   __restrict__ qzeros,
                   const float* __restrict__ scales,
                   const float* __restrict__ bias,
                   float* __restrict__ out)
{
    __shared__ __align__(16) unsigned char Asm[BM * 64 * 2];   // 32 KB
    __shared__ __align__(16) unsigned char Bsm[BN * 64 * 2];   // 16 KB

    const int tid  = threadIdx.x;
    const int lane = tid & 63;
    const int wid  = tid >> 6;           // 0..7
    const int wr   = (wid >> 1) * 64;    // wave row offset (0,64,128,192)
    const int wc   = (wid & 1) * 64;     // wave col offset (0,64)

    // XCD-aware bijective swizzle (gridDim.x = 1376 = 8*172)
    int bid = blockIdx.x;
    const int cpx = gridDim.x >> 3;
    bid = (bid & 7) * cpx + (bid >> 3);
    const int bm0 = (bid / NT_N) * BM;
    const int bn0 = (bid % NT_N) * BN;

    // ---- A staging: 2 threads/row, 64B each (4 x b128)
    const int arow  = tid >> 1;          // 0..255
    const int ahalf = tid & 1;
    unsigned char* aw = Asm + arow * 128;
    const int asw = (arow & 7) << 4;

    // ---- B staging: col n = tid&127, row-quad tid>>7 (rows bk8q, bk8q+4)
    const int bnn  = tid & 127;
    const int bk8q = tid >> 7;           // 0..3
    const int ngl  = bn0 + bnn;
    const int* qwp = qweight + (size_t)bk8q * N_DIM + ngl;   // pre-offset by bk8q
    unsigned char* bw = Bsm + bnn * 128;
    const int bsw = bnn & 7;

    const unsigned mu = 0xE400E400u;                    // (-1024,-1024) fp16
    const __half2 m1024 = *(const __half2*)&mu;

    // ---- fragment constants
    const int frow = lane & 15;
    const int kb8  = lane >> 4;
    const int fsw  = frow & 7;

    f32x4 acc[4][4];
#pragma unroll
    for (int m = 0; m < 4; ++m)
#pragma unroll
        for (int n = 0; n < 4; ++n)
            acc[m][n] = (f32x4){0.f, 0.f, 0.f, 0.f};

    __half2 scp = __half2{}, nzp = __half2{};

    for (int kt = 0; kt < K_DIM / 64; ++kt) {
        const int k0 = kt * 64;

        if ((k0 & 127) == 0) {           // new group (128 k = 2 k-steps)
            const int g = k0 >> 7;
            const float sc = scales[(size_t)g * N_DIM + ngl];
            const unsigned zq = (unsigned)qzeros[(size_t)g * NZ8 + (ngl >> 3)];
            const float zf = (float)((zq >> ((ngl & 7) * 4)) & 15u);
            const __half sh = __float2half_rn(sc);
            const __half nh = __float2half_rn(-sc * zf);
            scp = __half2(sh, sh);
            nzp = __half2(nh, nh);
        }

        // ---- stage A
        if constexpr (APATH == 0) {
            const __half* src = xh + (size_t)(bm0 + arow) * K_DIM + k0 + ahalf * 32;
#pragma unroll
            for (int i = 0; i < 4; ++i) {
                const f16x8 v = *(const f16x8*)(src + i * 8);
                *(f16x8*)(aw + ((((ahalf * 4 + i) << 4) ^ asw))) = v;
            }
        } else {
            const float* src = x + (size_t)(bm0 + arow) * K_DIM + k0 + ahalf * 32;
#pragma unroll
            for (int c = 0; c < 4; ++c) {
                const float4 f0 = *(const float4*)(src + c * 8);
                const float4 f1 = *(const float4*)(src + c * 8 + 4);
                union { __half2 h2[4]; f16x8 v; } p;
                p.h2[0] = __floats2half2_rn(f0.x, f1.x);
                p.h2[1] = __floats2half2_rn(f0.y, f1.y);
                p.h2[2] = __floats2half2_rn(f0.z, f1.z);
                p.h2[3] = __floats2half2_rn(f0.w, f1.w);
                *(f16x8*)(aw + ((((ahalf * 4 + c) << 4) ^ asw))) = p.v;
            }
        }

        // ---- stage B: magic dequant, 2 int32/thread
        //   global qweight row = bk8q (in qwp) + kt*8 + 4*i  ==  kt*8 + r   [r9 bug: was kt*8+r here, double-counting bk8q]
#pragma unroll
        for (int i = 0; i < 2; ++i) {
            const int r = bk8q + 4 * i;                  // local LDS chunk row 0..7
            const unsigned q = (unsigned)qwp[(size_t)(kt * 8 + 4 * i) * N_DIM];
            union { __half2 h2[4]; f16x8 v; } p;
#pragma unroll
            for (int d = 0; d < 4; ++d) {
                unsigned t = ((q >> (4 * d)) & 0x000F000Fu) | 0x64006400u;
                const __half2 th = *(const __half2*)&t;  // (1024+w_d, 1024+w_{d+4})
                p.h2[d] = __hfma2(__hadd2(th, m1024), scp, nzp);  // sc*(w-z)
            }
            *(f16x8*)(bw + ((r ^ bsw) << 4)) = p.v;
        }

        __syncthreads();

        // ---- compute: 2 k-halves x 4x4 MFMA (fp16)
#pragma unroll
        for (int kh = 0; kh < 2; ++kh) {
            const int ksl = (kh << 2) + kb8;             // 16B slot 0..7
            f16x8 af[4], bfr[4];
#pragma unroll
            for (int m = 0; m < 4; ++m) {
                const int row = wr + m * 16 + frow;
                af[m] = *(const f16x8*)(Asm + row * 128 + (((ksl ^ fsw) << 4)));
            }
#pragma unroll
            for (int n = 0; n < 4; ++n) {
                const int nn = wc + n * 16 + frow;
                bfr[n] = *(const f16x8*)(Bsm + nn * 128 + (((ksl ^ fsw) << 4)));
            }
#pragma unroll
            for (int m = 0; m < 4; ++m)
#pragma unroll
                for (int n = 0; n < 4; ++n)
                    acc[m][n] = __builtin_amdgcn_mfma_f32_16x16x32_f16(
                        af[m], bfr[n], acc[m][n], 0, 0, 0);
        }

        __syncthreads();
    }

    // ---- epilogue: C row=(lane>>4)*4+j, col=lane&15 (m89 layout)
    const int crow0 = (lane >> 4) << 2;
    const int ccol  = lane & 15;
#pragma unroll
    for (int n = 0; n < 4; ++n) {
        const int col = bn0 + wc + n * 16 + ccol;
        const float bv = bias[col];
#pragma unroll
        for (int m = 0; m < 4; ++m) {
            const int row = bm0 + wr + m * 16 + crow0;
#pragma unroll
            for (int j = 0; j < 4; ++j)
                out[(size_t)(row + j) * N_DIM + col] = acc[m][n][j] + bv;
        }
    }
}

extern "C" void kernel_launch(void* const* d_in, const int* in_sizes, int n_in,
                              void* d_out, int out_size, void* d_ws, size_t ws_size,
                              hipStream_t stream)
{
    const float* x   = (const float*)d_in[0];
    const int*   qw  = (const int*)d_in[1];
    const int*   qz  = (const int*)d_in[2];
    const float* scl = (const float*)d_in[3];
    const float* bs  = (const float*)d_in[4];
    float* out = (float*)d_out;

    const int M = in_sizes[0] / K_DIM;               // 4096
    const size_t xh_bytes = (size_t)M * K_DIM * 2;   // 33.6 MB
    dim3 grid((M / BM) * NT_N);                      // 16*86 = 1376

    if (ws_size >= xh_bytes) {
        __half* xh = (__half*)d_ws;
        const int nchunks = M * K_DIM / 8;
        hipLaunchKernelGGL(r10_xcvt, dim3(2048), dim3(256), 0, stream, x, xh, nchunks);
        hipLaunchKernelGGL((r10_gptq_mfma<0>), grid, dim3(512), 0, stream,
                           x, xh, qw, qz, scl, bs, out);
    } else {
        hipLaunchKernelGGL((r10_gptq_mfma<1>), grid, dim3(512), 0, stream,
                           x, (const __half*)nullptr, qw, qz, scl, bs, out);
    }
}

// Round 11
// 407.160 us; speedup vs baseline: 58.5816x; 1.0172x over previous
//
#include <hip/hip_runtime.h>
#include <hip/hip_fp16.h>

#define K_DIM 4096
#define N_DIM 11008
#define NZ8   1376          // N_DIM/8
#define BM    256
#define BN    256
#define BK    64
#define NT_N  43            // N_DIM/BN
#define NKT   64            // K_DIM/BK
#define ATB   32768         // A tile bytes = BM*BK*2

typedef _Float16 f16x8 __attribute__((ext_vector_type(8)));
typedef float    f32x4 __attribute__((ext_vector_type(4)));

__device__ __forceinline__ f16x8 dq8(unsigned q, __half2 scp, __half2 nzp)
{
    const unsigned mu = 0xE400E400u;                 // (-1024,-1024) fp16
    const __half2 m1024 = *(const __half2*)&mu;
    union { __half2 h2[4]; f16x8 v; } p;
#pragma unroll
    for (int d = 0; d < 4; ++d) {
        unsigned t = ((q >> (4 * d)) & 0x000F000Fu) | 0x64006400u;
        p.h2[d] = __hfma2(__hadd2(*(const __half2*)&t, m1024), scp, nzp);  // sc*(w-z)
    }
    return p.v;
}

// ---- pre-pass: x f32 -> fp16 into ws, TILED + pre-swizzled + k-interleaved.
// Tile (mt,kt) = 256 rows x 64 k at offset (mt*64+kt)*32KB; within tile,
// 16B chunk w: row=w>>3, physical slot s=w&7 holds logical slot ls=s^(row&7),
// i.e. k in [kt*64+ls*8, +8) in order (k0,k4,k1,k5,k2,k6,k3,k7).
// GEMM then stages A with linear global_load_lds and reads with the XOR swizzle.
__global__ __launch_bounds__(256)
void r11_xcvt(const float* __restrict__ x, __half* __restrict__ xh, int nchunks)
{
    int c = blockIdx.x * 256 + threadIdx.x;
    const int stride = gridDim.x * 256;
    for (; c < nchunks; c += stride) {
        const int w    = c & 2047;
        const int tidx = c >> 11;
        const int row  = w >> 3;
        const int s    = w & 7;
        const int ls   = s ^ (row & 7);
        const int mt   = tidx >> 6;        // tidx / NKT
        const int kt   = tidx & 63;
        const size_t gm = (size_t)mt * 256 + row;
        const int kb   = kt * 64 + ls * 8;
        const float4 f0 = *(const float4*)(x + gm * K_DIM + kb);
        const float4 f1 = *(const float4*)(x + gm * K_DIM + kb + 4);
        union { __half2 h2[4]; int4 v; } p;
        p.h2[0] = __floats2half2_rn(f0.x, f1.x);
        p.h2[1] = __floats2half2_rn(f0.y, f1.y);
        p.h2[2] = __floats2half2_rn(f0.z, f1.z);
        p.h2[3] = __floats2half2_rn(f0.w, f1.w);
        ((int4*)xh)[c] = p.v;
    }
}

// APATH1 fallback: inline f32->fp16 convert + swizzled ds_write (no ws).
__device__ __forceinline__ void stage_a_cvt(const float* __restrict__ x,
                                            unsigned char* __restrict__ abuf,
                                            int bm0, int kt, int arow, int ahalf, int asw)
{
    const float* src = x + (size_t)(bm0 + arow) * K_DIM + kt * 64 + ahalf * 32;
    unsigned char* aw = abuf + arow * 128;
#pragma unroll
    for (int c = 0; c < 4; ++c) {
        const float4 f0 = *(const float4*)(src + c * 8);
        const float4 f1 = *(const float4*)(src + c * 8 + 4);
        union { __half2 h2[4]; f16x8 v; } p;
        p.h2[0] = __floats2half2_rn(f0.x, f1.x);
        p.h2[1] = __floats2half2_rn(f0.y, f1.y);
        p.h2[2] = __floats2half2_rn(f0.z, f1.z);
        p.h2[3] = __floats2half2_rn(f0.w, f1.w);
        *(f16x8*)(aw + ((((ahalf * 4 + c) << 4) ^ asw))) = p.v;
    }
}

// ---- fused GEMM: 256x256 tile, BK=64, 8 waves (2M x 4N), wave-tile 128x64.
// Double-buffered LDS (128 KB), ONE barrier per k-step; stage issued before
// the MFMA block (T3 minimum-2-phase recipe), dequant+writes after.
template<int APATH>
__global__ __launch_bounds__(512, 2)
void r11_gemm(const float* __restrict__ x,
              const __half* __restrict__ xh,
              const int*   __restrict__ qweight,
              const int*   __restrict__ qzeros,
              const float* __restrict__ scales,
              const float* __restrict__ bias,
              float* __restrict__ out)
{
    __shared__ __align__(16) unsigned char Asm[2][ATB];   // 64 KB
    __shared__ __align__(16) unsigned char Bsm[2][ATB];   // 64 KB

    const int tid  = threadIdx.x;
    const int lane = tid & 63;
    const int wid  = tid >> 6;
    const int wr   = (wid >> 2) * 128;   // wave M offset (0,128)
    const int wc   = (wid & 3) * 64;     // wave N offset (0,64,128,192)

    // XCD-aware bijective swizzle (gridDim.x = 688 = 8*86)
    int bid = blockIdx.x;
    const int cpx = gridDim.x >> 3;
    bid = (bid & 7) * cpx + (bid >> 3);
    const int bm0 = (bid / NT_N) * BM;
    const int bn0 = (bid % NT_N) * BN;

    // ---- B staging: col bnn, row-set {bq, bq+2, bq+4, bq+6}
    const int bnn = tid & 255;
    const int bq  = tid >> 8;            // 0..1
    const int ngl = bn0 + bnn;
    const int* qwp = qweight + (size_t)bq * N_DIM + ngl;   // pre-offset by bq
    const int bsw = bnn & 7;

    // ---- A staging (APATH0): tiled pre-swizzled xh, linear global_load_lds
    const char* agp = (const char*)xh + ((size_t)(bm0 >> 8) * NKT) * ATB + tid * 16;

    // ---- A staging (APATH1 fallback)
    const int arow = tid >> 1, ahalf = tid & 1;
    const int asw  = (arow & 7) << 4;

    // ---- fragment constants (row&7 == frow&7 since offsets are mult of 8)
    const int frow = lane & 15, kb8 = lane >> 4, fsw = frow & 7;

    f32x4 acc[8][4];
#pragma unroll
    for (int m = 0; m < 8; ++m)
#pragma unroll
        for (int n = 0; n < 4; ++n)
            acc[m][n] = (f32x4){0.f, 0.f, 0.f, 0.f};

    __half2 scp, nzp;
    {   // group-0 dequant scalars
        const float sc = scales[ngl];
        const unsigned zq = (unsigned)qzeros[ngl >> 3];
        const float zf = (float)((zq >> ((ngl & 7) * 4)) & 15u);
        const __half sh = __float2half_rn(sc), nh = __float2half_rn(-sc * zf);
        scp = __half2(sh, sh); nzp = __half2(nh, nh);
    }

    // ---- prologue: stage tile 0 into buffer 0
    if constexpr (APATH == 0) {
#pragma unroll
        for (int i = 0; i < 4; ++i)
            __builtin_amdgcn_global_load_lds((const unsigned int*)(agp + i * 8192),
                                             (unsigned int*)&Asm[0][tid * 16 + i * 8192],
                                             16, 0, 0);
    } else {
        stage_a_cvt(x, &Asm[0][0], bm0, 0, arow, ahalf, asw);
    }
    {
        unsigned q[4];
#pragma unroll
        for (int i = 0; i < 4; ++i) q[i] = (unsigned)qwp[(size_t)(2 * i) * N_DIM];
#pragma unroll
        for (int i = 0; i < 4; ++i)
            *(f16x8*)(&Bsm[0][bnn * 128 + (((bq + 2 * i) ^ bsw) << 4)]) = dq8(q[i], scp, nzp);
    }
    __syncthreads();

    for (int kt = 0; kt < NKT; ++kt) {
        const int cur = kt & 1, nxt = cur ^ 1;
        unsigned qn[4];
        const bool hn = (kt + 1 < NKT);

        // ---- issue next-tile stage BEFORE compute (latency hides under MFMA)
        if (hn) {
            if constexpr (APATH == 0) {
                const char* ag = agp + (size_t)(kt + 1) * ATB;
#pragma unroll
                for (int i = 0; i < 4; ++i)
                    __builtin_amdgcn_global_load_lds((const unsigned int*)(ag + i * 8192),
                                                     (unsigned int*)&Asm[nxt][tid * 16 + i * 8192],
                                                     16, 0, 0);
            }
#pragma unroll
            for (int i = 0; i < 4; ++i)
                qn[i] = (unsigned)qwp[(size_t)((kt + 1) * 8 + 2 * i) * N_DIM];
            if (((kt + 1) & 1) == 0) {   // next tile starts a new group
                const int g = (kt + 1) >> 1;
                const float sc = scales[(size_t)g * N_DIM + ngl];
                const unsigned zq = (unsigned)qzeros[(size_t)g * NZ8 + (ngl >> 3)];
                const float zf = (float)((zq >> ((ngl & 7) * 4)) & 15u);
                const __half sh = __float2half_rn(sc), nh = __float2half_rn(-sc * zf);
                scp = __half2(sh, sh); nzp = __half2(nh, nh);
            }
        }

        // ---- compute current tile: 2 kh x 8 m x 4 n MFMA
#pragma unroll
        for (int kh = 0; kh < 2; ++kh) {
            const int ksl = (kh << 2) + kb8;
            f16x8 bfr[4];
#pragma unroll
            for (int n = 0; n < 4; ++n) {
                const int nn = wc + n * 16 + frow;
                bfr[n] = *(const f16x8*)(&Bsm[cur][nn * 128 + (((ksl ^ fsw) << 4))]);
            }
#pragma unroll
            for (int m = 0; m < 8; ++m) {
                const int row = wr + m * 16 + frow;
                const f16x8 af = *(const f16x8*)(&Asm[cur][row * 128 + (((ksl ^ fsw) << 4))]);
#pragma unroll
                for (int n = 0; n < 4; ++n)
                    acc[m][n] = __builtin_amdgcn_mfma_f32_16x16x32_f16(
                        af, bfr[n], acc[m][n], 0, 0, 0);
            }
        }

        // ---- finish next-tile stage (dequant + LDS writes), then one barrier
        if (hn) {
            if constexpr (APATH == 1)
                stage_a_cvt(x, &Asm[nxt][0], bm0, kt + 1, arow, ahalf, asw);
#pragma unroll
            for (int i = 0; i < 4; ++i)
                *(f16x8*)(&Bsm[nxt][bnn * 128 + (((bq + 2 * i) ^ bsw) << 4)]) = dq8(qn[i], scp, nzp);
        }
        __syncthreads();
    }

    // ---- epilogue: C row=(lane>>4)*4+j, col=lane&15 (m89 layout)
    const int crow0 = (lane >> 4) << 2, ccol = lane & 15;
#pragma unroll
    for (int n = 0; n < 4; ++n) {
        const int col = bn0 + wc + n * 16 + ccol;
        const float bv = bias[col];
#pragma unroll
        for (int m = 0; m < 8; ++m) {
            const int row = bm0 + wr + m * 16 + crow0;
#pragma unroll
            for (int j = 0; j < 4; ++j)
                out[(size_t)(row + j) * N_DIM + col] = acc[m][n][j] + bv;
        }
    }
}

extern "C" void kernel_launch(void* const* d_in, const int* in_sizes, int n_in,
                              void* d_out, int out_size, void* d_ws, size_t ws_size,
                              hipStream_t stream)
{
    const float* x   = (const float*)d_in[0];
    const int*   qw  = (const int*)d_in[1];
    const int*   qz  = (const int*)d_in[2];
    const float* scl = (const float*)d_in[3];
    const float* bs  = (const float*)d_in[4];
    float* out = (float*)d_out;

    const int M = in_sizes[0] / K_DIM;               // 4096
    const size_t xh_bytes = (size_t)M * K_DIM * 2;   // 33.6 MB
    dim3 grid((M / BM) * NT_N);                      // 16*43 = 688 (div by 8)

    if (ws_size >= xh_bytes) {
        __half* xh = (__half*)d_ws;
        const int nchunks = M * K_DIM / 8;
        hipLaunchKernelGGL(r11_xcvt, dim3(2048), dim3(256), 0, stream, x, xh, nchunks);
        hipLaunchKernelGGL((r11_gemm<0>), grid, dim3(512), 0, stream,
                           x, xh, qw, qz, scl, bs, out);
    } else {
        hipLaunchKernelGGL((r11_gemm<1>), grid, dim3(512), 0, stream,
                           x, (const __half*)nullptr, qw, qz, scl, bs, out);
    }
}